// Round 1
// 790.643 us; speedup vs baseline: 1.4163x; 1.4163x over previous
//
#include <hip/hip_runtime.h>

#define D 128

// ---------------- int degree histogram ----------------
__global__ void k_deg(const int* __restrict__ dst, int* __restrict__ deg, int E) {
    int e = blockIdx.x * blockDim.x + threadIdx.x;
    if (e < E) atomicAdd(&deg[dst[e]], 1);
}

// ---------------- single-block exclusive scan (rowptr) ----------------
__global__ __launch_bounds__(1024) void k_scan(const int* __restrict__ deg,
                                               int* __restrict__ rowptr, int N) {
    __shared__ int wsum[16];
    __shared__ int wscan[16];
    __shared__ int s_carry;
    const int tid = threadIdx.x, lane = tid & 63, wid = tid >> 6;
    if (tid == 0) s_carry = 0;
    __syncthreads();
    for (int base = 0; base < N; base += 1024) {
        int i = base + tid;
        int v = (i < N) ? deg[i] : 0;
        int x = v;
        #pragma unroll
        for (int off = 1; off < 64; off <<= 1) {
            int t = __shfl_up(x, off);
            if (lane >= off) x += t;
        }
        if (lane == 63) wsum[wid] = x;
        __syncthreads();
        if (wid == 0) {
            int s = (lane < 16) ? wsum[lane] : 0;
            #pragma unroll
            for (int off = 1; off < 16; off <<= 1) {
                int t = __shfl_up(s, off);
                if (lane >= off) s += t;
            }
            if (lane < 16) wscan[lane] = s;
        }
        __syncthreads();
        int woff = (wid > 0) ? wscan[wid - 1] : 0;
        int incl = x + woff;
        int carry = s_carry;
        if (i < N) rowptr[i] = carry + incl - v;
        __syncthreads();
        if (tid == 1023) s_carry = carry + wscan[15];
        __syncthreads();
    }
    if (threadIdx.x == 0) rowptr[N] = s_carry;
}

// ---------------- CSR fill ----------------
__global__ void k_fill(const int* __restrict__ src, const int* __restrict__ dst,
                       const int* __restrict__ rowptr, int* __restrict__ cursor,
                       int* __restrict__ csr, int E) {
    int e = blockIdx.x * blockDim.x + threadIdx.x;
    if (e >= E) return;
    int d = dst[e];
    int pos = rowptr[d] + atomicAdd(&cursor[d], 1);
    csr[pos] = src[e];
}

// ---------------- gather-mean aggregation: one wave per dst node ----------------
__global__ __launch_bounds__(256) void k_agg(const int* __restrict__ rowptr,
                                             const int* __restrict__ csr,
                                             const float* __restrict__ xin,
                                             float* __restrict__ agg, int N) {
    int w = (int)((blockIdx.x * 256u + threadIdx.x) >> 6);
    int lane = threadIdx.x & 63;
    if (w >= N) return;
    int s0 = rowptr[w], s1 = rowptr[w + 1];
    float2 acc0 = make_float2(0.f, 0.f);
    float2 acc1 = make_float2(0.f, 0.f);
    for (int p = s0; p < s1; p += 64) {
        int m = s1 - p; if (m > 64) m = 64;
        int my = (p + lane < s1) ? csr[p + lane] : 0;
        int j = 0;
        for (; j + 1 < m; j += 2) {
            int sa = __shfl(my, j);
            int sb = __shfl(my, j + 1);
            float2 va = reinterpret_cast<const float2*>(xin)[(size_t)sa * 64 + lane];
            float2 vb = reinterpret_cast<const float2*>(xin)[(size_t)sb * 64 + lane];
            acc0.x += va.x; acc0.y += va.y;
            acc1.x += vb.x; acc1.y += vb.y;
        }
        if (j < m) {
            int sa = __shfl(my, j);
            float2 va = reinterpret_cast<const float2*>(xin)[(size_t)sa * 64 + lane];
            acc0.x += va.x; acc0.y += va.y;
        }
    }
    float inv = 1.0f / fmaxf((float)(s1 - s0), 1.0f);
    reinterpret_cast<float2*>(agg)[(size_t)w * 64 + lane] =
        make_float2((acc0.x + acc1.x) * inv, (acc0.y + acc1.y) * inv);
}

// ---------------- register-tiled SGEMM ----------------
// out[i,j] = act( sum_m sum_k A_m[i,k] * W_m[j,k]  + bias[j] )
// Tile: 128 rows x 128 cols per 256-thread block; 8x8 micro-tile per thread.
// A staged row-major [128][32+4]; W staged transposed [32][128+4].
template <bool RELU, int NMAT>
__global__ __launch_bounds__(256) void k_gemm(
    const float* __restrict__ A0, const float* __restrict__ A1,
    const float* __restrict__ W0, const float* __restrict__ W1,
    const float* __restrict__ bias,
    float* __restrict__ out, int N)
{
    __shared__ float sA[128 * 36];   // rows x (BK=32 + pad4)   = 18 KB
    __shared__ float sW[32 * 132];   // k x (128 cols + pad4)   = 16.5 KB

    const int tid = threadIdx.x;
    const int tx  = tid & 15;        // col group: cols tx*4 and 64+tx*4
    const int ty  = tid >> 4;        // row group: rows ty*4 and 64+ty*4
    const int base = blockIdx.x * 128;

    float acc[2][2][4][4];           // [rowhalf][colhalf][ri][ci]
    #pragma unroll
    for (int a = 0; a < 2; ++a)
        #pragma unroll
        for (int b = 0; b < 2; ++b)
            #pragma unroll
            for (int i = 0; i < 4; ++i)
                #pragma unroll
                for (int j = 0; j < 4; ++j)
                    acc[a][b][i][j] = 0.0f;

    const int NCH = NMAT * 4;        // K-chunks of 32
    for (int c_i = 0; c_i < NCH; ++c_i) {
        const float* Asrc = (NMAT == 2 && c_i >= 4) ? A1 : A0;
        const float* Wsrc = (NMAT == 2 && c_i >= 4) ? W1 : W0;
        const int kc = (c_i & 3) * 32;

        __syncthreads();   // previous chunk's reads done before overwrite

        // stage A chunk: 128 rows x 32 k  (1024 float4, 4 per thread)
        #pragma unroll
        for (int it = 0; it < 4; ++it) {
            int idx = it * 256 + tid;
            int row = idx >> 3, kq = idx & 7;
            int grow = base + row;
            if (grow >= N) grow = N - 1;            // clamp; tail rows unused
            float4 v = *reinterpret_cast<const float4*>(
                &Asrc[(size_t)grow * D + kc + kq * 4]);
            *reinterpret_cast<float4*>(&sA[row * 36 + kq * 4]) = v;
        }
        // stage W chunk transposed: sW[k][j] = W[j][kc+k]
        #pragma unroll
        for (int it = 0; it < 4; ++it) {
            int idx = it * 256 + tid;
            int j = idx >> 3, kq = idx & 7;
            float4 v = *reinterpret_cast<const float4*>(&Wsrc[j * D + kc + kq * 4]);
            sW[(kq * 4 + 0) * 132 + j] = v.x;
            sW[(kq * 4 + 1) * 132 + j] = v.y;
            sW[(kq * 4 + 2) * 132 + j] = v.z;
            sW[(kq * 4 + 3) * 132 + j] = v.w;
        }
        __syncthreads();

        // compute: 32 k-steps, unrolled by 4
        #pragma unroll
        for (int kk = 0; kk < 32; kk += 4) {
            float4 av[2][4];   // [rowhalf][ri] : 4 k-values each
            #pragma unroll
            for (int rh = 0; rh < 2; ++rh)
                #pragma unroll
                for (int ri = 0; ri < 4; ++ri)
                    av[rh][ri] = *reinterpret_cast<const float4*>(
                        &sA[(rh * 64 + ty * 4 + ri) * 36 + kk]);
            float4 wv[4][2];   // [kq][colhalf] : 4 cols each
            #pragma unroll
            for (int kq = 0; kq < 4; ++kq)
                #pragma unroll
                for (int c = 0; c < 2; ++c)
                    wv[kq][c] = *reinterpret_cast<const float4*>(
                        &sW[(kk + kq) * 132 + c * 64 + tx * 4]);
            #pragma unroll
            for (int kq = 0; kq < 4; ++kq) {
                #pragma unroll
                for (int rh = 0; rh < 2; ++rh) {
                    #pragma unroll
                    for (int ri = 0; ri < 4; ++ri) {
                        float a = reinterpret_cast<const float*>(&av[rh][ri])[kq];
                        #pragma unroll
                        for (int c = 0; c < 2; ++c) {
                            float4 w = wv[kq][c];
                            acc[rh][c][ri][0] = fmaf(a, w.x, acc[rh][c][ri][0]);
                            acc[rh][c][ri][1] = fmaf(a, w.y, acc[rh][c][ri][1]);
                            acc[rh][c][ri][2] = fmaf(a, w.z, acc[rh][c][ri][2]);
                            acc[rh][c][ri][3] = fmaf(a, w.w, acc[rh][c][ri][3]);
                        }
                    }
                }
            }
        }
    }

    // epilogue: bias + activation + store
    float4 b4[2];
    b4[0] = *reinterpret_cast<const float4*>(&bias[tx * 4]);
    b4[1] = *reinterpret_cast<const float4*>(&bias[64 + tx * 4]);
    #pragma unroll
    for (int rh = 0; rh < 2; ++rh) {
        #pragma unroll
        for (int ri = 0; ri < 4; ++ri) {
            int row = base + rh * 64 + ty * 4 + ri;
            if (row < N) {
                #pragma unroll
                for (int c = 0; c < 2; ++c) {
                    float4 o;
                    o.x = acc[rh][c][ri][0] + b4[c].x;
                    o.y = acc[rh][c][ri][1] + b4[c].y;
                    o.z = acc[rh][c][ri][2] + b4[c].z;
                    o.w = acc[rh][c][ri][3] + b4[c].w;
                    if (RELU) {
                        o.x = fmaxf(o.x, 0.0f); o.y = fmaxf(o.y, 0.0f);
                        o.z = fmaxf(o.z, 0.0f); o.w = fmaxf(o.w, 0.0f);
                    }
                    *reinterpret_cast<float4*>(&out[(size_t)row * D + c * 64 + tx * 4]) = o;
                }
            }
        }
    }
}

extern "C" void kernel_launch(void* const* d_in, const int* in_sizes, int n_in,
                              void* d_out, int out_size, void* d_ws, size_t ws_size,
                              hipStream_t stream) {
    const float* x   = (const float*)d_in[0];
    const int*   ei  = (const int*)d_in[1];
    const float* Wl0 = (const float*)d_in[2];
    const float* bl0 = (const float*)d_in[3];
    const float* Wr0 = (const float*)d_in[4];
    const float* Wl1 = (const float*)d_in[5];
    const float* bl1 = (const float*)d_in[6];
    const float* Wr1 = (const float*)d_in[7];
    const float* Wv  = (const float*)d_in[8];
    const float* bv  = (const float*)d_in[9];
    const float* Wt  = (const float*)d_in[10];
    const float* bt  = (const float*)d_in[11];

    const int N = in_sizes[0] / D;       // 100000
    const int E = in_sizes[1] / 2;       // 1600000
    const int* srcv = ei;
    const int* dstv = ei + E;

    float* out  = (float*)d_out;
    float* h    = out;                        // [0, N*D)      final output 0
    float* h1   = out + (size_t)N * D;        // scratch, later x_vision
    float* aggb = out + 2 * (size_t)N * D;    // scratch, later x_text

    // CSR workspace: deg(N) | rowptr(N+1) | cursor(N) | csr(E)  — ints
    size_t need = ((size_t)(3 * N + 1) + (size_t)E) * sizeof(int);
    int* wsI = (ws_size >= need) ? (int*)d_ws
                                 : (int*)h;   // fallback: h region is free until layer-1 gemm
    int* degI   = wsI;
    int* rowptr = wsI + N;
    int* cursor = wsI + 2 * N + 1;
    int* csr    = wsI + 2 * N + 1 + N;

    hipMemsetAsync(degI,   0, (size_t)N * sizeof(int), stream);
    hipMemsetAsync(cursor, 0, (size_t)N * sizeof(int), stream);
    k_deg <<<(E + 255) / 256, 256, 0, stream>>>(dstv, degI, E);
    k_scan<<<1, 1024, 0, stream>>>(degI, rowptr, N);
    k_fill<<<(E + 255) / 256, 256, 0, stream>>>(srcv, dstv, rowptr, cursor, csr, E);

    const int agg_blocks  = (int)(((size_t)N * 64 + 255) / 256);
    const int gemm_blocks = (N + 127) / 128;

    // ---- layer 0 ----
    k_agg<<<agg_blocks, 256, 0, stream>>>(rowptr, csr, x, aggb, N);
    k_gemm<true, 2><<<gemm_blocks, 256, 0, stream>>>(aggb, x, Wl0, Wr0, bl0, h1, N);

    // ---- layer 1 ----
    k_agg<<<agg_blocks, 256, 0, stream>>>(rowptr, csr, h1, aggb, N);
    k_gemm<false, 2><<<gemm_blocks, 256, 0, stream>>>(aggb, h1, Wl1, Wr1, bl1, h, N);

    // ---- heads: xv = relu(h@Wv^T+bv), xt = relu(h@Wt^T+bt) ----
    k_gemm<true, 1><<<gemm_blocks, 256, 0, stream>>>(h, nullptr, Wv, nullptr, bv,
                                                     out + (size_t)N * D, N);
    k_gemm<true, 1><<<gemm_blocks, 256, 0, stream>>>(h, nullptr, Wt, nullptr, bt,
                                                     out + 2 * (size_t)N * D, N);
}